// Round 1
// 447.845 us; speedup vs baseline: 1.1081x; 1.1081x over previous
//
#include <hip/hip_runtime.h>

#define BB 4
#define NN 1024
#define DD 256
#define NHEADS 8
#define NPTS 4
#define NKSAMP 10
#define HHF 200
#define WWF 200
#define HWF (HHF*WWF)
#define KTOT 2304   // 2048 (g) + 256 (qe residual via combined Wq@Wout)

typedef __attribute__((ext_vector_type(8))) short bf16x8;
typedef __attribute__((ext_vector_type(4))) float f32x4;

__device__ __forceinline__ unsigned short f2bf(float f){
    unsigned u = __float_as_uint(f);
    return (unsigned short)((u + 0x7FFFu + ((u >> 16) & 1u)) >> 16);
}
__device__ __forceinline__ void load_bf16x8(const unsigned short* p, float* v){
    int4 t = *reinterpret_cast<const int4*>(p);
    unsigned q0 = (unsigned)t.x, q1 = (unsigned)t.y, q2 = (unsigned)t.z, q3 = (unsigned)t.w;
    v[0] = __uint_as_float(q0 << 16); v[1] = __uint_as_float(q0 & 0xFFFF0000u);
    v[2] = __uint_as_float(q1 << 16); v[3] = __uint_as_float(q1 & 0xFFFF0000u);
    v[4] = __uint_as_float(q2 << 16); v[5] = __uint_as_float(q2 & 0xFFFF0000u);
    v[6] = __uint_as_float(q3 << 16); v[7] = __uint_as_float(q3 & 0xFFFF0000u);
}
__device__ __forceinline__ void store_bf16x8(unsigned short* p, const float* v){
    int4 t;
    t.x = (int)((unsigned)f2bf(v[0]) | ((unsigned)f2bf(v[1]) << 16));
    t.y = (int)((unsigned)f2bf(v[2]) | ((unsigned)f2bf(v[3]) << 16));
    t.z = (int)((unsigned)f2bf(v[4]) | ((unsigned)f2bf(v[5]) << 16));
    t.w = (int)((unsigned)f2bf(v[6]) | ((unsigned)f2bf(v[7]) << 16));
    *reinterpret_cast<int4*>(p) = t;
}

// bev (B, C, HW) f32 -> bevT (B, HW, C) bf16 bits
__global__ __launch_bounds__(256) void transpose_kernel(const float* __restrict__ bev,
                                                        unsigned short* __restrict__ bevT){
    __shared__ unsigned short tile[32][33];
    int b  = blockIdx.z;
    int c0 = blockIdx.y * 32;
    int p0 = blockIdx.x * 32;
    int tx = threadIdx.x & 31;
    int ty = threadIdx.x >> 5;   // 0..7
    const float* src = bev + (size_t)b * DD * HWF;
    #pragma unroll
    for (int i = 0; i < 4; i++){
        int c = c0 + ty + i*8;
        tile[ty + i*8][tx] = f2bf(src[(size_t)c * HWF + p0 + tx]);
    }
    __syncthreads();
    unsigned short* dst = bevT + (size_t)b * HWF * DD;
    #pragma unroll
    for (int i = 0; i < 4; i++){
        int p = p0 + ty + i*8;
        dst[(size_t)p * DD + c0 + tx] = tile[tx][ty + i*8];
    }
}

// ---------------- prep: combine all weight-only linear algebra -------------------
// Wdoout = Wdo@Wout (computed per-block in LDS, never materialized)
// WgT[n][h*256+c]   = sum_j Wval[c][h*32+j] * Wdoout[h*32+j][n]      (bf16, n-major)
// WgT[n][2048+c]    = (Wq@Wout)[c][n]                                 (bf16)
// Wqoa[c][o]        = (Wq@[Woff|Wattn])[c][o], o<64 off, o>=64 attn   (f32)
// bqoa[o]           = bq@[Woff|Wattn] + [boff|battn]
// Bh[h][n]          = bval_h @ Wdoout_h     ;  bconst[n] = (bdo+bq)@Wout + bout
// blocks: 0..31 WgT head tiles, 32..47 WgT qe tiles, 48..51 Wqoa, 52 Bh/bconst
__global__ __launch_bounds__(256) void prep_kernel(
    const float* __restrict__ Wq,   const float* __restrict__ bq,
    const float* __restrict__ Wval, const float* __restrict__ bval,
    const float* __restrict__ Woff, const float* __restrict__ boff,
    const float* __restrict__ Wattn,const float* __restrict__ battn,
    const float* __restrict__ Wdo,  const float* __restrict__ bdo,
    const float* __restrict__ Wout, const float* __restrict__ bout,
    unsigned short* __restrict__ WgT,
    float* __restrict__ Wqoa, float* __restrict__ bqoa,
    float* __restrict__ Bh,   float* __restrict__ bconst)
{
    __shared__ __align__(16) char smem[42496];
    const int bx  = blockIdx.x;
    const int tid = threadIdx.x;

    if (bx < 32){
        // ---- WgT head tile: h = bx>>2, n0 = (bx&3)*64 ----
        float (*WoutS)[64] = (float(*)[64])smem;                 // [128][64]
        float (*DhT)[36]   = (float(*)[36])(smem + 128*64*4);    // [64][36] Wdoout^T slice
        const int h   = bx >> 2;
        const int n0  = (bx & 3) * 64;
        const int j   = tid >> 3;        // 0..31
        const int nn0 = (tid & 7) * 8;   // 0..56
        float acc[8];
        #pragma unroll
        for (int u = 0; u < 8; u++) acc[u] = 0.f;
        for (int p = 0; p < 2; p++){
            if (p) __syncthreads();
            #pragma unroll
            for (int i = 0; i < 8; i++){
                int idx = tid + i*256;
                int t = idx >> 4, c4 = (idx & 15)*4;
                *reinterpret_cast<float4*>(&WoutS[t][c4]) =
                    *reinterpret_cast<const float4*>(Wout + (size_t)(p*128 + t)*256 + n0 + c4);
            }
            __syncthreads();
            const float* wdop = Wdo + (size_t)(h*32 + j)*256 + p*128;
            for (int t = 0; t < 128; t++){
                float wdo = wdop[t];
                float4 w0 = *reinterpret_cast<const float4*>(&WoutS[t][nn0]);
                float4 w1 = *reinterpret_cast<const float4*>(&WoutS[t][nn0+4]);
                acc[0] += wdo*w0.x; acc[1] += wdo*w0.y; acc[2] += wdo*w0.z; acc[3] += wdo*w0.w;
                acc[4] += wdo*w1.x; acc[5] += wdo*w1.y; acc[6] += wdo*w1.z; acc[7] += wdo*w1.w;
            }
        }
        #pragma unroll
        for (int u = 0; u < 8; u++) DhT[nn0 + u][j] = acc[u];
        __syncthreads();
        // phase 2: c = tid; WgT[n0+nn][h*256+c] = sum_j Wval[c][h*32+j]*DhT[nn][j]
        float wv[32];
        #pragma unroll
        for (int q4 = 0; q4 < 8; q4++){
            float4 v = *reinterpret_cast<const float4*>(Wval + (size_t)tid*256 + h*32 + q4*4);
            wv[q4*4+0]=v.x; wv[q4*4+1]=v.y; wv[q4*4+2]=v.z; wv[q4*4+3]=v.w;
        }
        for (int nn = 0; nn < 64; nn++){
            float s = 0.f;
            #pragma unroll
            for (int q4 = 0; q4 < 8; q4++){
                float4 d = *reinterpret_cast<const float4*>(&DhT[nn][q4*4]);
                s += wv[q4*4+0]*d.x + wv[q4*4+1]*d.y + wv[q4*4+2]*d.z + wv[q4*4+3]*d.w;
            }
            WgT[(size_t)(n0 + nn)*KTOT + h*256 + tid] = f2bf(s);
        }
    } else if (bx < 48){
        // ---- WgT qe tile: n0 = ((bx-32)>>2)*64, c0 = ((bx-32)&3)*64 ----
        const int idx2 = bx - 32;
        const int n0 = (idx2 >> 2) * 64;
        const int c0 = (idx2 & 3) * 64;
        float (*WoutS)[64] = (float(*)[64])smem;                 // [64][64]
        float (*WqS)[65]   = (float(*)[65])(smem + 64*64*4);     // [64][65] padded
        const int lc  = tid & 63;
        const int grp = tid >> 6;
        float acc[16];
        #pragma unroll
        for (int u = 0; u < 16; u++) acc[u] = 0.f;
        for (int p = 0; p < 4; p++){
            if (p) __syncthreads();
            #pragma unroll
            for (int i = 0; i < 4; i++){
                int idx = tid + i*256;
                int r = idx >> 4, c4 = (idx & 15)*4;
                *reinterpret_cast<float4*>(&WoutS[r][c4]) =
                    *reinterpret_cast<const float4*>(Wout + (size_t)(p*64 + r)*256 + n0 + c4);
                float4 wq = *reinterpret_cast<const float4*>(Wq + (size_t)(c0 + r)*256 + p*64 + c4);
                WqS[r][c4+0]=wq.x; WqS[r][c4+1]=wq.y; WqS[r][c4+2]=wq.z; WqS[r][c4+3]=wq.w;
            }
            __syncthreads();
            for (int jj = 0; jj < 64; jj++){
                float wq = WqS[lc][jj];
                #pragma unroll
                for (int u4 = 0; u4 < 4; u4++){
                    float4 w = *reinterpret_cast<const float4*>(&WoutS[jj][grp*16 + u4*4]);
                    acc[u4*4+0] += wq*w.x; acc[u4*4+1] += wq*w.y;
                    acc[u4*4+2] += wq*w.z; acc[u4*4+3] += wq*w.w;
                }
            }
        }
        #pragma unroll
        for (int u = 0; u < 16; u++)
            WgT[(size_t)(n0 + grp*16 + u)*KTOT + 2048 + c0 + lc] = f2bf(acc[u]);
    } else if (bx < 52){
        // ---- Wqoa rows c0..c0+63, all 96 cols; bx==48 also does bqoa ----
        const int c0 = (bx - 48) * 64;
        float (*WS)[96]  = (float(*)[96])smem;                   // [64][96]
        float (*WqS)[65] = (float(*)[65])(smem + 64*96*4);       // [64][65]
        const int lc  = tid & 63;
        const int grp = tid >> 6;       // o-range grp*24..+24
        float acc[24];
        #pragma unroll
        for (int u = 0; u < 24; u++) acc[u] = 0.f;
        float bacc = 0.f;
        for (int p = 0; p < 4; p++){
            if (p) __syncthreads();
            #pragma unroll
            for (int i = 0; i < 6; i++){
                int idx = tid + i*256;
                int r = idx / 24, c4 = (idx % 24) * 4;
                float4 v;
                if (c4 < 64) v = *reinterpret_cast<const float4*>(Woff  + (size_t)(p*64 + r)*64 + c4);
                else         v = *reinterpret_cast<const float4*>(Wattn + (size_t)(p*64 + r)*32 + (c4 - 64));
                WS[r][c4+0]=v.x; WS[r][c4+1]=v.y; WS[r][c4+2]=v.z; WS[r][c4+3]=v.w;
            }
            #pragma unroll
            for (int i = 0; i < 4; i++){
                int idx = tid + i*256;
                int r = idx >> 4, c4 = (idx & 15)*4;
                float4 wq = *reinterpret_cast<const float4*>(Wq + (size_t)(c0 + r)*256 + p*64 + c4);
                WqS[r][c4+0]=wq.x; WqS[r][c4+1]=wq.y; WqS[r][c4+2]=wq.z; WqS[r][c4+3]=wq.w;
            }
            __syncthreads();
            for (int jj = 0; jj < 64; jj++){
                float wq = WqS[lc][jj];
                #pragma unroll
                for (int u4 = 0; u4 < 6; u4++){
                    float4 w = *reinterpret_cast<const float4*>(&WS[jj][grp*24 + u4*4]);
                    acc[u4*4+0] += wq*w.x; acc[u4*4+1] += wq*w.y;
                    acc[u4*4+2] += wq*w.z; acc[u4*4+3] += wq*w.w;
                }
            }
            if (bx == 48 && tid < 96){
                for (int jj = 0; jj < 64; jj++) bacc += bq[p*64 + jj] * WS[jj][tid];
            }
        }
        #pragma unroll
        for (int u = 0; u < 24; u++)
            Wqoa[(size_t)(c0 + lc)*96 + grp*24 + u] = acc[u];
        if (bx == 48 && tid < 96)
            bqoa[tid] = bacc + (tid < 64 ? boff[tid] : battn[tid - 64]);
    } else {
        // ---- bx == 52: Bh[8][256] and bconst[256] ----
        float (*vhS)[256] = (float(*)[256])smem;     // [8][256]
        const int t = tid;
        for (int h = 0; h < 8; h++){
            float s = 0.f;
            #pragma unroll
            for (int jj = 0; jj < 32; jj++)
                s += bval[h*32 + jj] * Wdo[(size_t)(h*32 + jj)*256 + t];
            vhS[h][t] = s;
        }
        __syncthreads();
        float bh[8];
        #pragma unroll
        for (int h = 0; h < 8; h++) bh[h] = 0.f;
        float bc = 0.f;
        for (int k = 0; k < 256; k++){
            float w  = Wout[(size_t)k*256 + t];
            bc += (bdo[k] + bq[k]) * w;
            #pragma unroll
            for (int h = 0; h < 8; h++) bh[h] += vhS[h][k] * w;
        }
        #pragma unroll
        for (int h = 0; h < 8; h++) Bh[h*256 + t] = bh[h];
        bconst[t] = bc + bout[t];
    }
}

// ---------------- oa GEMM direct from qe (combined Wqoa) + coords epilogue --------
__global__ __launch_bounds__(256) void oacoords_kernel(
    const float* __restrict__ qe, const float* __restrict__ ctrl, const float* __restrict__ pc,
    const float* __restrict__ Wqoa, const float* __restrict__ bqoa,
    float* __restrict__ coords,      // per (m,h): 4 pts x {x,y,w}
    float* __restrict__ wsb)         // per (m,h): valid-weight sum
{
    __shared__ __align__(16) char smem[256*68*4];      // As, then reused as oaS
    float (*As)[68] = (float(*)[68])smem;
    __shared__ float cen_s[64][2];
    const int m0  = blockIdx.x * 64;
    const int tid = threadIdx.x;

    {   // stage A^T (qe rows m0..m0+63)
        int r  = tid >> 2;
        int kb = (tid & 3) * 4;
        #pragma unroll
        for (int kk = 0; kk < 16; kk++){
            int k = kb + kk*16;
            float4 v = *reinterpret_cast<const float4*>(qe + (size_t)(m0 + r)*256 + k);
            As[k+0][r] = v.x; As[k+1][r] = v.y; As[k+2][r] = v.z; As[k+3][r] = v.w;
        }
    }
    if (tid < 64){   // bezier centers
        int m = m0 + tid;
        float cx[4], cy[4];
        #pragma unroll
        for (int i = 0; i < 4; i++){
            cx[i] = ctrl[(size_t)m*8 + i*2 + 0];
            cy[i] = ctrl[(size_t)m*8 + i*2 + 1];
        }
        float lox = pc[0], loy = pc[1];
        float spx = pc[3] - lox, spy = pc[4] - loy;
        float sx = 0.f, sy = 0.f;
        for (int k = 0; k < NKSAMP; k++){
            float t = (float)k / (float)(NKSAMP - 1);
            float u = 1.f - t;
            float c0 = u*u*u, c1 = 3.f*u*u*t, c2 = 3.f*u*t*t, c3 = t*t*t;
            float dx = c0*cx[0] + c1*cx[1] + c2*cx[2] + c3*cx[3];
            float dy = c0*cy[0] + c1*cy[1] + c2*cy[2] + c3*cy[3];
            float rx = fminf(fmaxf((dx - lox)/spx, 0.01f), 0.99f);
            float ry = fminf(fmaxf((dy - loy)/spy, 0.01f), 0.99f);
            sx += rx; sy += ry;
        }
        cen_s[tid][0] = (sx / (float)NKSAMP) * (float)WWF - 0.5f;
        cen_s[tid][1] = (sy / (float)NKSAMP) * (float)HHF - 0.5f;
    }
    __syncthreads();

    const int ti = tid & 15;
    const int tj = tid >> 4;
    float ao[4][4], aa[4][2];
    #pragma unroll
    for (int i = 0; i < 4; i++){
        #pragma unroll
        for (int j = 0; j < 4; j++) ao[i][j] = 0.f;
        aa[i][0] = 0.f; aa[i][1] = 0.f;
    }
    #pragma unroll 4
    for (int c = 0; c < 256; c++){
        float4 a = *reinterpret_cast<const float4*>(&As[c][ti*4]);
        float av[4] = {a.x, a.y, a.z, a.w};
        float4 bo = *reinterpret_cast<const float4*>(Wqoa + (size_t)c*96 + tj*4);
        float2 ba = *reinterpret_cast<const float2*>(Wqoa + (size_t)c*96 + 64 + tj*2);
        #pragma unroll
        for (int i = 0; i < 4; i++){
            ao[i][0] += av[i]*bo.x; ao[i][1] += av[i]*bo.y;
            ao[i][2] += av[i]*bo.z; ao[i][3] += av[i]*bo.w;
            aa[i][0] += av[i]*ba.x; aa[i][1] += av[i]*ba.y;
        }
    }
    __syncthreads();                 // As fully consumed
    float* oaS = (float*)smem;       // 64 x 96, reuse As storage
    #pragma unroll
    for (int i = 0; i < 4; i++){
        int r = ti*4 + i;
        #pragma unroll
        for (int j = 0; j < 4; j++) oaS[r*96 + tj*4 + j] = ao[i][j] + bqoa[tj*4 + j];
        oaS[r*96 + 64 + tj*2 + 0] = aa[i][0] + bqoa[64 + tj*2 + 0];
        oaS[r*96 + 64 + tj*2 + 1] = aa[i][1] + bqoa[64 + tj*2 + 1];
    }
    __syncthreads();

    for (int idx = tid; idx < 512; idx += 256){
        int r = idx >> 3, h = idx & 7;
        int m = m0 + r;
        const float* row = oaS + r*96;
        float a0 = row[64 + h*4 + 0], a1 = row[64 + h*4 + 1];
        float a2 = row[64 + h*4 + 2], a3 = row[64 + h*4 + 3];
        float mx = fmaxf(fmaxf(a0, a1), fmaxf(a2, a3));
        float e0 = __expf(a0 - mx), e1 = __expf(a1 - mx);
        float e2 = __expf(a2 - mx), e3 = __expf(a3 - mx);
        float inv = 1.f / (e0 + e1 + e2 + e3);
        float wp[4] = {e0*inv, e1*inv, e2*inv, e3*inv};
        float cxp = cen_s[r][0], cyp = cen_s[r][1];
        float* cp = coords + ((size_t)m*8 + h)*12;
        float wsum = 0.f;
        #pragma unroll
        for (int p = 0; p < 4; p++){
            float x = cxp + row[h*8 + p*2 + 0];
            float y = cyp + row[h*8 + p*2 + 1];
            cp[p*3 + 0] = x; cp[p*3 + 1] = y; cp[p*3 + 2] = wp[p];
            float fx = floorf(x), fy = floorf(y);
            int x0 = (int)fx, y0 = (int)fy;
            float wx = x - fx, wy = y - fy;
            bool vx0 = (unsigned)x0 < WWF, vx1 = (unsigned)(x0+1) < WWF;
            bool vy0 = (unsigned)y0 < HHF, vy1 = (unsigned)(y0+1) < HHF;
            float w = wp[p];
            if (vy0 && vx0) wsum += w*(1.f-wx)*(1.f-wy);
            if (vy0 && vx1) wsum += w*wx*(1.f-wy);
            if (vy1 && vx0) wsum += w*(1.f-wx)*wy;
            if (vy1 && vx1) wsum += w*wx*wy;
        }
        wsb[(size_t)m*8 + h] = wsum;
    }
}

// ---------------- gather: g[m][h*256+c] = sum over pts/corners of w * bev[...][c] ---
// 2 queries/block (grid 2048) -> 8 blocks/CU for better L3-latency hiding
template<bool TRANS>
__global__ __launch_bounds__(256) void gather_kernel(
    const unsigned short* __restrict__ bevT,   // (B,HW,C) bf16 bits
    const float* __restrict__ bev,             // (B,C,HW) f32
    const float* __restrict__ coords,
    unsigned short* __restrict__ g)
{
    const int m0  = blockIdx.x * 2;
    const int b   = m0 >> 10;
    const int sub = threadIdx.x & 31;
    const int grp = threadIdx.x >> 5;

    for (int it = 0; it < 2; it++){
        int rh = it*8 + grp;           // 0..15
        int m  = m0 + (rh >> 3);
        int h  = rh & 7;
        float acc[8] = {0.f,0.f,0.f,0.f,0.f,0.f,0.f,0.f};
        const float* cp = coords + ((size_t)m*8 + h)*12;

        #pragma unroll
        for (int p = 0; p < 4; p++){
            float x = cp[p*3+0], y = cp[p*3+1], w = cp[p*3+2];
            float fx = floorf(x), fy = floorf(y);
            int x0 = (int)fx, y0 = (int)fy;
            float wx = x - fx, wy = y - fy;
            int   xs[4]  = {x0, x0+1, x0,   x0+1};
            int   ys[4]  = {y0, y0,   y0+1, y0+1};
            float ws4[4] = {w*(1.f-wx)*(1.f-wy), w*wx*(1.f-wy), w*(1.f-wx)*wy, w*wx*wy};
            #pragma unroll
            for (int cidx = 0; cidx < 4; cidx++){
                int xi = xs[cidx], yi = ys[cidx];
                if ((unsigned)xi < WWF && (unsigned)yi < HHF){
                    float wgt = ws4[cidx];
                    if (TRANS){
                        const unsigned short* rowp =
                            bevT + (((size_t)b*HWF + yi*WWF + xi)*DD + sub*8);
                        float v[8]; load_bf16x8(rowp, v);
                        #pragma unroll
                        for (int i = 0; i < 8; i++) acc[i] += wgt * v[i];
                    } else {
                        size_t base = ((size_t)b*DD + sub*8)*HWF + (size_t)(yi*WWF + xi);
                        #pragma unroll
                        for (int i = 0; i < 8; i++) acc[i] += wgt * bev[base + (size_t)i*HWF];
                    }
                }
            }
        }
        store_bf16x8(g + ((size_t)m*2048 + h*256 + sub*8), acc);
    }
}

// ---------------- final: out = [g | bf16(qe)] @ Wg^T  + wsb@Bh + bconst (MFMA) ------
// block: 64 rows x 64 cols, 4 waves (16 rows each); per wave 4 n-tiles of 16x16.
// k-permutation chosen identically for A and B fragments -> result independent of
// the HW's internal k ordering. D layout: col=lane&15, row=(lane>>4)*4+reg (m89).
__global__ __launch_bounds__(256) void final_kernel(
    const unsigned short* __restrict__ g,     // [4096][2048] bf16
    const float* __restrict__ qe,             // [4096][256] f32
    const unsigned short* __restrict__ WgT,   // [256][KTOT] bf16
    const float* __restrict__ wsb,            // [4096][8]
    const float* __restrict__ Bh,             // [8][256]
    const float* __restrict__ bconst,         // [256]
    float* __restrict__ out)                  // [4096][256]
{
    const int n0   = blockIdx.x * 64;
    const int m0   = blockIdx.y * 64;
    const int w    = threadIdx.x >> 6;
    const int l    = threadIdx.x & 63;
    const int lrow = l & 15;
    const int lk   = l >> 4;
    const int mrow = m0 + w*16 + lrow;

    f32x4 acc0 = {0.f,0.f,0.f,0.f};
    f32x4 acc1 = {0.f,0.f,0.f,0.f};
    f32x4 acc2 = {0.f,0.f,0.f,0.f};
    f32x4 acc3 = {0.f,0.f,0.f,0.f};

    const unsigned short* Ap = g   + (size_t)mrow*2048 + lk*8;
    const unsigned short* Bp = WgT + (size_t)(n0 + lrow)*KTOT + lk*8;

    #pragma unroll 4
    for (int k0 = 0; k0 < 2048; k0 += 32){
        bf16x8 a  = *reinterpret_cast<const bf16x8*>(Ap + k0);
        bf16x8 b0 = *reinterpret_cast<const bf16x8*>(Bp + k0);
        bf16x8 b1 = *reinterpret_cast<const bf16x8*>(Bp + 16*KTOT + k0);
        bf16x8 b2 = *reinterpret_cast<const bf16x8*>(Bp + 32*KTOT + k0);
        bf16x8 b3 = *reinterpret_cast<const bf16x8*>(Bp + 48*KTOT + k0);
        acc0 = __builtin_amdgcn_mfma_f32_16x16x32_bf16(a, b0, acc0, 0, 0, 0);
        acc1 = __builtin_amdgcn_mfma_f32_16x16x32_bf16(a, b1, acc1, 0, 0, 0);
        acc2 = __builtin_amdgcn_mfma_f32_16x16x32_bf16(a, b2, acc2, 0, 0, 0);
        acc3 = __builtin_amdgcn_mfma_f32_16x16x32_bf16(a, b3, acc3, 0, 0, 0);
    }
    // residual part: k' = 2048..2303 sourced from qe (convert f32->bf16 on the fly)
    const float* Qp = qe + (size_t)mrow*256 + lk*8;
    #pragma unroll
    for (int k0 = 0; k0 < 256; k0 += 32){
        float4 qa = *reinterpret_cast<const float4*>(Qp + k0);
        float4 qb = *reinterpret_cast<const float4*>(Qp + k0 + 4);
        union { unsigned short u[8]; bf16x8 v; } cu;
        cu.u[0]=f2bf(qa.x); cu.u[1]=f2bf(qa.y); cu.u[2]=f2bf(qa.z); cu.u[3]=f2bf(qa.w);
        cu.u[4]=f2bf(qb.x); cu.u[5]=f2bf(qb.y); cu.u[6]=f2bf(qb.z); cu.u[7]=f2bf(qb.w);
        bf16x8 b0 = *reinterpret_cast<const bf16x8*>(Bp + 2048 + k0);
        bf16x8 b1 = *reinterpret_cast<const bf16x8*>(Bp + 16*KTOT + 2048 + k0);
        bf16x8 b2 = *reinterpret_cast<const bf16x8*>(Bp + 32*KTOT + 2048 + k0);
        bf16x8 b3 = *reinterpret_cast<const bf16x8*>(Bp + 48*KTOT + 2048 + k0);
        acc0 = __builtin_amdgcn_mfma_f32_16x16x32_bf16(cu.v, b0, acc0, 0, 0, 0);
        acc1 = __builtin_amdgcn_mfma_f32_16x16x32_bf16(cu.v, b1, acc1, 0, 0, 0);
        acc2 = __builtin_amdgcn_mfma_f32_16x16x32_bf16(cu.v, b2, acc2, 0, 0, 0);
        acc3 = __builtin_amdgcn_mfma_f32_16x16x32_bf16(cu.v, b3, acc3, 0, 0, 0);
    }

    // epilogue: + bconst + wsb@Bh
    float wsrow[4][8];
    #pragma unroll
    for (int i = 0; i < 4; i++){
        int r = m0 + w*16 + lk*4 + i;
        float4 wa = *reinterpret_cast<const float4*>(wsb + (size_t)r*8);
        float4 wb = *reinterpret_cast<const float4*>(wsb + (size_t)r*8 + 4);
        wsrow[i][0]=wa.x; wsrow[i][1]=wa.y; wsrow[i][2]=wa.z; wsrow[i][3]=wa.w;
        wsrow[i][4]=wb.x; wsrow[i][5]=wb.y; wsrow[i][6]=wb.z; wsrow[i][7]=wb.w;
    }
    const f32x4 accs[4] = {acc0, acc1, acc2, acc3};
    #pragma unroll
    for (int nt = 0; nt < 4; nt++){
        int c = n0 + nt*16 + lrow;
        float bcv = bconst[c];
        float bhv[8];
        #pragma unroll
        for (int h = 0; h < 8; h++) bhv[h] = Bh[h*256 + c];
        #pragma unroll
        for (int i = 0; i < 4; i++){
            int r = m0 + w*16 + lk*4 + i;
            float v = accs[nt][i] + bcv;
            #pragma unroll
            for (int h = 0; h < 8; h++) v += wsrow[i][h]*bhv[h];
            out[(size_t)r*256 + c] = v;
        }
    }
}

extern "C" void kernel_launch(void* const* d_in, const int* in_sizes, int n_in,
                              void* d_out, int out_size, void* d_ws, size_t ws_size,
                              hipStream_t stream)
{
    (void)in_sizes; (void)n_in; (void)out_size;
    float* out = (float*)d_out;
    char*  ws  = (char*)d_ws;

    // workspace layout (256B-aligned); bevT last so the fallback tier works
    const size_t OF_CO  = 0;                                  // coords 4096*8*48
    const size_t OF_WSB = OF_CO  + (size_t)4096*8*48;         //  1,572,864
    const size_t OF_WGT = OF_WSB + (size_t)4096*8*4;          //  1,703,936
    const size_t OF_WQO = OF_WGT + (size_t)256*KTOT*2;        //  2,883,584
    const size_t OF_BQO = OF_WQO + (size_t)256*96*4;          //  2,981,888
    const size_t OF_BH  = OF_BQO + 512;                       //  2,982,400
    const size_t OF_BC  = OF_BH  + (size_t)8*256*4;           //  2,990,592
    const size_t OF_G   = OF_BC  + 1024;                      //  2,991,616
    const size_t OF_BT  = OF_G   + (size_t)4096*2048*2;       // 19,768,832
    const size_t NEED   = OF_BT  + (size_t)BB*HWF*DD*2;       //101,688,832

    float*          coords = (float*)(ws + OF_CO);
    float*          wsb    = (float*)(ws + OF_WSB);
    unsigned short* WgT    = (unsigned short*)(ws + OF_WGT);
    float*          Wqoa   = (float*)(ws + OF_WQO);
    float*          bqoa   = (float*)(ws + OF_BQO);
    float*          Bh     = (float*)(ws + OF_BH);
    float*          bconst = (float*)(ws + OF_BC);
    unsigned short* g      = (unsigned short*)(ws + OF_G);
    unsigned short* bevT   = (unsigned short*)(ws + OF_BT);

    const float* qe    = (const float*)d_in[0];
    const float* ctrl  = (const float*)d_in[1];
    const float* bev   = (const float*)d_in[2];
    const float* pc    = (const float*)d_in[4];
    const float* Wq    = (const float*)d_in[5];
    const float* bq    = (const float*)d_in[6];
    const float* Wval  = (const float*)d_in[7];
    const float* bval  = (const float*)d_in[8];
    const float* Woff  = (const float*)d_in[9];
    const float* boff  = (const float*)d_in[10];
    const float* Wattn = (const float*)d_in[11];
    const float* battn = (const float*)d_in[12];
    const float* Wdo   = (const float*)d_in[13];
    const float* bdo   = (const float*)d_in[14];
    const float* Wout  = (const float*)d_in[15];
    const float* bout  = (const float*)d_in[16];

    const bool haveT = (ws_size >= NEED);

    // weight combining (independent of activations)
    prep_kernel<<<53, 256, 0, stream>>>(Wq, bq, Wval, bval, Woff, boff, Wattn, battn,
                                        Wdo, bdo, Wout, bout,
                                        WgT, Wqoa, bqoa, Bh, bconst);
    if (haveT)
        transpose_kernel<<<dim3(HWF/32, DD/32, BB), 256, 0, stream>>>(bev, bevT);
    // offsets/attn/coords straight from qe via combined weights (no q-GEMM)
    oacoords_kernel<<<64, 256, 0, stream>>>(qe, ctrl, pc, Wqoa, bqoa, coords, wsb);
    // gather
    if (haveT)
        gather_kernel<true ><<<2048, 256, 0, stream>>>(bevT, bev, coords, g);
    else
        gather_kernel<false><<<2048, 256, 0, stream>>>(bevT, bev, coords, g);
    // single fused back-end GEMM (MFMA bf16): out = [g|qe]@WgT^T + wsb@Bh + bconst
    final_kernel<<<dim3(4, 64), 256, 0, stream>>>(g, qe, WgT, wsb, Bh, bconst, out);
}

// Round 2
// 412.377 us; speedup vs baseline: 1.2034x; 1.0860x over previous
//
#include <hip/hip_runtime.h>

#define BB 4
#define NN 1024
#define DD 256
#define NHEADS 8
#define NPTS 4
#define NKSAMP 10
#define HHF 200
#define WWF 200
#define HWF (HHF*WWF)
#define KTOT 2304   // 2048 (g) + 256 (qe residual via combined Wq@Wout)

typedef __attribute__((ext_vector_type(8))) short bf16x8;
typedef __attribute__((ext_vector_type(4))) float f32x4;

__device__ __forceinline__ unsigned short f2bf(float f){
    unsigned u = __float_as_uint(f);
    return (unsigned short)((u + 0x7FFFu + ((u >> 16) & 1u)) >> 16);
}
__device__ __forceinline__ void load_bf16x8(const unsigned short* p, float* v){
    int4 t = *reinterpret_cast<const int4*>(p);
    unsigned q0 = (unsigned)t.x, q1 = (unsigned)t.y, q2 = (unsigned)t.z, q3 = (unsigned)t.w;
    v[0] = __uint_as_float(q0 << 16); v[1] = __uint_as_float(q0 & 0xFFFF0000u);
    v[2] = __uint_as_float(q1 << 16); v[3] = __uint_as_float(q1 & 0xFFFF0000u);
    v[4] = __uint_as_float(q2 << 16); v[5] = __uint_as_float(q2 & 0xFFFF0000u);
    v[6] = __uint_as_float(q3 << 16); v[7] = __uint_as_float(q3 & 0xFFFF0000u);
}
__device__ __forceinline__ void store_bf16x8(unsigned short* p, const float* v){
    int4 t;
    t.x = (int)((unsigned)f2bf(v[0]) | ((unsigned)f2bf(v[1]) << 16));
    t.y = (int)((unsigned)f2bf(v[2]) | ((unsigned)f2bf(v[3]) << 16));
    t.z = (int)((unsigned)f2bf(v[4]) | ((unsigned)f2bf(v[5]) << 16));
    t.w = (int)((unsigned)f2bf(v[6]) | ((unsigned)f2bf(v[7]) << 16));
    *reinterpret_cast<int4*>(p) = t;
}

// ================== K1: front  (oa-standalone | prep | transpose) ==================
// blocks [0,64)    : oa -- q = qe@Wq+bq (in-block), oa = q@[Woff|Wattn]+b, coords/wsb
// blocks [64,113)  : prep -- WgT (combined g/qe back-end weights), Bh, bconst
// blocks [113,...) : transpose -- bev (B,C,HW) f32 -> bevT (B,HW,C) bf16, 64x64 tiles
__global__ __launch_bounds__(256) void front_kernel(
    const float* __restrict__ qe,   const float* __restrict__ ctrl,
    const float* __restrict__ pc,
    const float* __restrict__ Wq,   const float* __restrict__ bq,
    const float* __restrict__ Wval, const float* __restrict__ bval,
    const float* __restrict__ Woff, const float* __restrict__ boff,
    const float* __restrict__ Wattn,const float* __restrict__ battn,
    const float* __restrict__ Wdo,  const float* __restrict__ bdo,
    const float* __restrict__ Wout, const float* __restrict__ bout,
    const float* __restrict__ bev,
    unsigned short* __restrict__ bevT,
    unsigned short* __restrict__ WgT,
    float* __restrict__ Bh, float* __restrict__ bconst,
    float* __restrict__ coords, float* __restrict__ wsb)
{
    __shared__ __align__(16) char smem[65536];
    const int bx  = blockIdx.x;
    const int tid = threadIdx.x;

    if (bx < 64){
        // ---------------- oa role: 64 query rows ----------------
        const int m0 = bx * 64;
        float (*As)[64] = (float(*)[64])smem;       // qe^T [256 k][64 r], exactly 64KB
        {
            int r  = tid >> 2;
            int kb = (tid & 3) * 4;
            #pragma unroll
            for (int kk = 0; kk < 16; kk++){
                int k = kb + kk*16;
                float4 v = *reinterpret_cast<const float4*>(qe + (size_t)(m0 + r)*256 + k);
                As[k+0][r] = v.x; As[k+1][r] = v.y; As[k+2][r] = v.z; As[k+3][r] = v.w;
            }
        }
        __syncthreads();
        const int ti = tid & 15;
        const int tj = tid >> 4;

        // phase B: q = qe@Wq + bq, held in regs as qreg[n-part][row i]
        float qreg[16][4];
        #pragma unroll
        for (int slab = 0; slab < 4; slab++){
            float acc[4][4];
            #pragma unroll
            for (int i = 0; i < 4; i++)
                #pragma unroll
                for (int j = 0; j < 4; j++) acc[i][j] = 0.f;
            #pragma unroll 4
            for (int c = 0; c < 256; c++){
                float4 a = *reinterpret_cast<const float4*>(&As[c][ti*4]);
                float av[4] = {a.x, a.y, a.z, a.w};
                float4 b = *reinterpret_cast<const float4*>(Wq + (size_t)c*256 + slab*64 + tj*4);
                float bv[4] = {b.x, b.y, b.z, b.w};
                #pragma unroll
                for (int i = 0; i < 4; i++)
                    #pragma unroll
                    for (int j = 0; j < 4; j++) acc[i][j] += av[i]*bv[j];
            }
            #pragma unroll
            for (int j = 0; j < 4; j++){
                float bqv = bq[slab*64 + tj*4 + j];
                #pragma unroll
                for (int i = 0; i < 4; i++) qreg[slab*4 + j][i] = acc[i][j] + bqv;
            }
        }
        __syncthreads();                 // As consumed
        float* qT = (float*)smem;        // q^T [256 n][64 r]
        #pragma unroll
        for (int t = 0; t < 16; t++){
            int n = (t >> 2)*64 + tj*4 + (t & 3);
            float4 v; v.x = qreg[t][0]; v.y = qreg[t][1]; v.z = qreg[t][2]; v.w = qreg[t][3];
            *reinterpret_cast<float4*>(&qT[(size_t)n*64 + ti*4]) = v;
        }
        __syncthreads();

        // phase C: oa = q @ [Woff|Wattn]
        float ao[4][4], aa[4][2];
        #pragma unroll
        for (int i = 0; i < 4; i++){
            #pragma unroll
            for (int j = 0; j < 4; j++) ao[i][j] = 0.f;
            aa[i][0] = 0.f; aa[i][1] = 0.f;
        }
        #pragma unroll 4
        for (int c = 0; c < 256; c++){
            float4 a = *reinterpret_cast<const float4*>(&qT[(size_t)c*64 + ti*4]);
            float av[4] = {a.x, a.y, a.z, a.w};
            float4 bo = *reinterpret_cast<const float4*>(Woff  + (size_t)c*64 + tj*4);
            float2 ba = *reinterpret_cast<const float2*>(Wattn + (size_t)c*32 + tj*2);
            #pragma unroll
            for (int i = 0; i < 4; i++){
                ao[i][0] += av[i]*bo.x; ao[i][1] += av[i]*bo.y;
                ao[i][2] += av[i]*bo.z; ao[i][3] += av[i]*bo.w;
                aa[i][0] += av[i]*ba.x; aa[i][1] += av[i]*ba.y;
            }
        }
        __syncthreads();                 // qT consumed
        float* oaS = (float*)smem;       // [64][96]
        #pragma unroll
        for (int i = 0; i < 4; i++){
            int r = ti*4 + i;
            #pragma unroll
            for (int j = 0; j < 4; j++) oaS[r*96 + tj*4 + j] = ao[i][j] + boff[tj*4 + j];
            oaS[r*96 + 64 + tj*2 + 0] = aa[i][0] + battn[tj*2 + 0];
            oaS[r*96 + 64 + tj*2 + 1] = aa[i][1] + battn[tj*2 + 1];
        }
        __syncthreads();

        // epilogue: per (r,h) softmax + bezier center (recomputed per thread) + coords
        const float lox = pc[0], loy = pc[1];
        const float spx = pc[3] - lox, spy = pc[4] - loy;
        for (int idx = tid; idx < 512; idx += 256){
            int r = idx >> 3, h = idx & 7;
            int m = m0 + r;
            // bezier center for row r (cheap, redundant across h)
            float cx[4], cy[4];
            #pragma unroll
            for (int i = 0; i < 4; i++){
                cx[i] = ctrl[(size_t)m*8 + i*2 + 0];
                cy[i] = ctrl[(size_t)m*8 + i*2 + 1];
            }
            float sx = 0.f, sy = 0.f;
            for (int k = 0; k < NKSAMP; k++){
                float t = (float)k / (float)(NKSAMP - 1);
                float u = 1.f - t;
                float c0 = u*u*u, c1 = 3.f*u*u*t, c2 = 3.f*u*t*t, c3 = t*t*t;
                float dx = c0*cx[0] + c1*cx[1] + c2*cx[2] + c3*cx[3];
                float dy = c0*cy[0] + c1*cy[1] + c2*cy[2] + c3*cy[3];
                float rx = fminf(fmaxf((dx - lox)/spx, 0.01f), 0.99f);
                float ry = fminf(fmaxf((dy - loy)/spy, 0.01f), 0.99f);
                sx += rx; sy += ry;
            }
            float cxp = (sx / (float)NKSAMP) * (float)WWF - 0.5f;
            float cyp = (sy / (float)NKSAMP) * (float)HHF - 0.5f;

            const float* row = oaS + r*96;
            float a0 = row[64 + h*4 + 0], a1 = row[64 + h*4 + 1];
            float a2 = row[64 + h*4 + 2], a3 = row[64 + h*4 + 3];
            float mx = fmaxf(fmaxf(a0, a1), fmaxf(a2, a3));
            float e0 = __expf(a0 - mx), e1 = __expf(a1 - mx);
            float e2 = __expf(a2 - mx), e3 = __expf(a3 - mx);
            float inv = 1.f / (e0 + e1 + e2 + e3);
            float wp[4] = {e0*inv, e1*inv, e2*inv, e3*inv};
            float* cp = coords + ((size_t)m*8 + h)*12;
            float wsum = 0.f;
            #pragma unroll
            for (int p = 0; p < 4; p++){
                float x = cxp + row[h*8 + p*2 + 0];
                float y = cyp + row[h*8 + p*2 + 1];
                cp[p*3 + 0] = x; cp[p*3 + 1] = y; cp[p*3 + 2] = wp[p];
                float fx = floorf(x), fy = floorf(y);
                int x0 = (int)fx, y0 = (int)fy;
                float wx = x - fx, wy = y - fy;
                bool vx0 = (unsigned)x0 < WWF, vx1 = (unsigned)(x0+1) < WWF;
                bool vy0 = (unsigned)y0 < HHF, vy1 = (unsigned)(y0+1) < HHF;
                float w = wp[p];
                if (vy0 && vx0) wsum += w*(1.f-wx)*(1.f-wy);
                if (vy0 && vx1) wsum += w*wx*(1.f-wy);
                if (vy1 && vx0) wsum += w*(1.f-wx)*wy;
                if (vy1 && vx1) wsum += w*wx*wy;
            }
            wsb[(size_t)m*8 + h] = wsum;
        }
    } else if (bx < 113){
        // ---------------- prep role ----------------
        const int bxp = bx - 64;
        if (bxp < 32){
            // WgT head tile: h = bxp>>2, n0 = (bxp&3)*64
            float (*WoutS)[64] = (float(*)[64])smem;                 // [128][64]
            float (*DhT)[36]   = (float(*)[36])(smem + 128*64*4);    // [64][36]
            const int h   = bxp >> 2;
            const int n0  = (bxp & 3) * 64;
            const int j   = tid >> 3;
            const int nn0 = (tid & 7) * 8;
            float acc[8];
            #pragma unroll
            for (int u = 0; u < 8; u++) acc[u] = 0.f;
            for (int p = 0; p < 2; p++){
                if (p) __syncthreads();
                #pragma unroll
                for (int i = 0; i < 8; i++){
                    int idx = tid + i*256;
                    int t = idx >> 4, c4 = (idx & 15)*4;
                    *reinterpret_cast<float4*>(&WoutS[t][c4]) =
                        *reinterpret_cast<const float4*>(Wout + (size_t)(p*128 + t)*256 + n0 + c4);
                }
                __syncthreads();
                const float* wdop = Wdo + (size_t)(h*32 + j)*256 + p*128;
                for (int t = 0; t < 128; t++){
                    float wdo = wdop[t];
                    float4 w0 = *reinterpret_cast<const float4*>(&WoutS[t][nn0]);
                    float4 w1 = *reinterpret_cast<const float4*>(&WoutS[t][nn0+4]);
                    acc[0] += wdo*w0.x; acc[1] += wdo*w0.y; acc[2] += wdo*w0.z; acc[3] += wdo*w0.w;
                    acc[4] += wdo*w1.x; acc[5] += wdo*w1.y; acc[6] += wdo*w1.z; acc[7] += wdo*w1.w;
                }
            }
            #pragma unroll
            for (int u = 0; u < 8; u++) DhT[nn0 + u][j] = acc[u];
            __syncthreads();
            float wv[32];
            #pragma unroll
            for (int q4 = 0; q4 < 8; q4++){
                float4 v = *reinterpret_cast<const float4*>(Wval + (size_t)tid*256 + h*32 + q4*4);
                wv[q4*4+0]=v.x; wv[q4*4+1]=v.y; wv[q4*4+2]=v.z; wv[q4*4+3]=v.w;
            }
            for (int nn = 0; nn < 64; nn++){
                float s = 0.f;
                #pragma unroll
                for (int q4 = 0; q4 < 8; q4++){
                    float4 d = *reinterpret_cast<const float4*>(&DhT[nn][q4*4]);
                    s += wv[q4*4+0]*d.x + wv[q4*4+1]*d.y + wv[q4*4+2]*d.z + wv[q4*4+3]*d.w;
                }
                WgT[(size_t)(n0 + nn)*KTOT + h*256 + tid] = f2bf(s);
            }
        } else if (bxp < 48){
            // WgT qe tile: (Wq@Wout)^T
            const int idx2 = bxp - 32;
            const int n0 = (idx2 >> 2) * 64;
            const int c0 = (idx2 & 3) * 64;
            float (*WoutS)[64] = (float(*)[64])smem;                 // [64][64]
            float (*WqS)[65]   = (float(*)[65])(smem + 64*64*4);     // [64][65]
            const int lc  = tid & 63;
            const int grp = tid >> 6;
            float acc[16];
            #pragma unroll
            for (int u = 0; u < 16; u++) acc[u] = 0.f;
            for (int p = 0; p < 4; p++){
                if (p) __syncthreads();
                #pragma unroll
                for (int i = 0; i < 4; i++){
                    int idx = tid + i*256;
                    int r = idx >> 4, c4 = (idx & 15)*4;
                    *reinterpret_cast<float4*>(&WoutS[r][c4]) =
                        *reinterpret_cast<const float4*>(Wout + (size_t)(p*64 + r)*256 + n0 + c4);
                    float4 wq = *reinterpret_cast<const float4*>(Wq + (size_t)(c0 + r)*256 + p*64 + c4);
                    WqS[r][c4+0]=wq.x; WqS[r][c4+1]=wq.y; WqS[r][c4+2]=wq.z; WqS[r][c4+3]=wq.w;
                }
                __syncthreads();
                for (int jj = 0; jj < 64; jj++){
                    float wq = WqS[lc][jj];
                    #pragma unroll
                    for (int u4 = 0; u4 < 4; u4++){
                        float4 w = *reinterpret_cast<const float4*>(&WoutS[jj][grp*16 + u4*4]);
                        acc[u4*4+0] += wq*w.x; acc[u4*4+1] += wq*w.y;
                        acc[u4*4+2] += wq*w.z; acc[u4*4+3] += wq*w.w;
                    }
                }
            }
            #pragma unroll
            for (int u = 0; u < 16; u++)
                WgT[(size_t)(n0 + grp*16 + u)*KTOT + 2048 + c0 + lc] = f2bf(acc[u]);
        } else {
            // Bh[8][256] and bconst[256]
            float (*vhS)[256] = (float(*)[256])smem;
            const int t = tid;
            for (int h = 0; h < 8; h++){
                float s = 0.f;
                #pragma unroll
                for (int jj = 0; jj < 32; jj++)
                    s += bval[h*32 + jj] * Wdo[(size_t)(h*32 + jj)*256 + t];
                vhS[h][t] = s;
            }
            __syncthreads();
            float bh[8];
            #pragma unroll
            for (int h = 0; h < 8; h++) bh[h] = 0.f;
            float bc = 0.f;
            for (int k = 0; k < 256; k++){
                float w  = Wout[(size_t)k*256 + t];
                bc += (bdo[k] + bq[k]) * w;
                #pragma unroll
                for (int h = 0; h < 8; h++) bh[h] += vhS[h][k] * w;
            }
            #pragma unroll
            for (int h = 0; h < 8; h++) Bh[h*256 + t] = bh[h];
            bconst[t] = bc + bout[t];
        }
    } else {
        // ---------------- transpose role: 64x64 tile via f32 LDS ----------------
        const int bxt = bx - 113;
        const int b   = bxt / 2500;
        const int r2  = bxt - b*2500;
        const int c0  = (r2 / 625) * 64;
        const int p0  = (r2 - (r2/625)*625) * 64;
        float (*T)[67] = (float(*)[67])smem;       // [64 p][67] (pitch 67: bank-spread)
        const float* src = bev + (size_t)b * DD * HWF;
        const int tx = tid & 15, ty = tid >> 4;
        #pragma unroll
        for (int q = 0; q < 4; q++){
            int c = c0 + q*16 + ty;
            float4 v = *reinterpret_cast<const float4*>(src + (size_t)c*HWF + p0 + tx*4);
            T[tx*4+0][q*16+ty] = v.x; T[tx*4+1][q*16+ty] = v.y;
            T[tx*4+2][q*16+ty] = v.z; T[tx*4+3][q*16+ty] = v.w;
        }
        __syncthreads();
        const int sx = tid & 7, sy = tid >> 3;     // sy 0..31
        unsigned short* dst = bevT + (size_t)b * HWF * DD;
        #pragma unroll
        for (int s = 0; s < 2; s++){
            int p = s*32 + sy;
            float v[8];
            #pragma unroll
            for (int u = 0; u < 8; u++) v[u] = T[p][sx*8+u];
            store_bf16x8(dst + (size_t)(p0 + p)*DD + c0 + sx*8, v);
        }
    }
}

// ================== K2: gather ==================
// g[m][h*256+c] = sum over pts/corners of w * bevT[...][c]; 2 queries/block
template<bool TRANS>
__global__ __launch_bounds__(256) void gather_kernel(
    const unsigned short* __restrict__ bevT,   // (B,HW,C) bf16 bits
    const float* __restrict__ bev,             // (B,C,HW) f32
    const float* __restrict__ coords,
    unsigned short* __restrict__ g)
{
    const int m0  = blockIdx.x * 2;
    const int b   = m0 >> 10;
    const int sub = threadIdx.x & 31;
    const int grp = threadIdx.x >> 5;

    for (int it = 0; it < 2; it++){
        int rh = it*8 + grp;           // 0..15
        int m  = m0 + (rh >> 3);
        int h  = rh & 7;
        float acc[8] = {0.f,0.f,0.f,0.f,0.f,0.f,0.f,0.f};
        const float* cp = coords + ((size_t)m*8 + h)*12;

        #pragma unroll
        for (int p = 0; p < 4; p++){
            float x = cp[p*3+0], y = cp[p*3+1], w = cp[p*3+2];
            float fx = floorf(x), fy = floorf(y);
            int x0 = (int)fx, y0 = (int)fy;
            float wx = x - fx, wy = y - fy;
            int   xs[4]  = {x0, x0+1, x0,   x0+1};
            int   ys[4]  = {y0, y0,   y0+1, y0+1};
            float ws4[4] = {w*(1.f-wx)*(1.f-wy), w*wx*(1.f-wy), w*(1.f-wx)*wy, w*wx*wy};
            #pragma unroll
            for (int cidx = 0; cidx < 4; cidx++){
                int xi = xs[cidx], yi = ys[cidx];
                if ((unsigned)xi < WWF && (unsigned)yi < HHF){
                    float wgt = ws4[cidx];
                    if (TRANS){
                        const unsigned short* rowp =
                            bevT + (((size_t)b*HWF + yi*WWF + xi)*DD + sub*8);
                        float v[8]; load_bf16x8(rowp, v);
                        #pragma unroll
                        for (int i = 0; i < 8; i++) acc[i] += wgt * v[i];
                    } else {
                        size_t base = ((size_t)b*DD + sub*8)*HWF + (size_t)(yi*WWF + xi);
                        #pragma unroll
                        for (int i = 0; i < 8; i++) acc[i] += wgt * bev[base + (size_t)i*HWF];
                    }
                }
            }
        }
        store_bf16x8(g + ((size_t)m*2048 + h*256 + sub*8), acc);
    }
}

// ================== K3: final  out = [g|bf16(qe)]@WgT^T + wsb@Bh + bconst ==========
// grid 256: 16-row m-tiles x full N=256. A panel (16x2048 bf16 = 64KB) staged in LDS
// with XOR-16B swizzle (conflict-free b128 reads). 4 waves, wave w -> n-slab w*64.
// D layout: col=lane&15, row=(lane>>4)*4+reg (m89-verified).
__global__ __launch_bounds__(256) void final_kernel(
    const unsigned short* __restrict__ g,     // [4096][2048] bf16
    const float* __restrict__ qe,             // [4096][256] f32
    const unsigned short* __restrict__ WgT,   // [256][KTOT] bf16
    const float* __restrict__ wsb,            // [4096][8]
    const float* __restrict__ Bh,             // [8][256]
    const float* __restrict__ bconst,         // [256]
    float* __restrict__ out)                  // [4096][256]
{
    __shared__ __align__(16) unsigned short As[16*2048];   // 64 KB, swizzled
    const int m0  = blockIdx.x * 16;
    const int tid = threadIdx.x;
    const int w    = tid >> 6;
    const int l    = tid & 63;
    const int lrow = l & 15;
    const int lk   = l >> 4;

    {   // stage A: rows m0..m0+15, k<2048 from g (already bf16 bits)
        int row  = tid >> 4;
        int lane = tid & 15;
        const unsigned short* gp = g + (size_t)(m0 + row)*2048;
        char* dstb = (char*)(As + row*2048);
        #pragma unroll
        for (int t = 0; t < 16; t++){
            int kbyte = t*256 + lane*16;
            int4 v = *reinterpret_cast<const int4*>((const char*)gp + kbyte);
            *reinterpret_cast<int4*>(dstb + (kbyte ^ ((row & 7) << 4))) = v;
        }
    }
    __syncthreads();

    f32x4 acc0 = {0.f,0.f,0.f,0.f};
    f32x4 acc1 = {0.f,0.f,0.f,0.f};
    f32x4 acc2 = {0.f,0.f,0.f,0.f};
    f32x4 acc3 = {0.f,0.f,0.f,0.f};

    const unsigned short* Bp = WgT + (size_t)(w*64 + lrow)*KTOT + lk*8;
    const char* Ab = (const char*)(As + lrow*2048);
    const int asw = (lrow & 7) << 4;

    #pragma unroll 4
    for (int k0 = 0; k0 < 2048; k0 += 32){
        bf16x8 a  = *reinterpret_cast<const bf16x8*>(Ab + (((k0 + lk*8)*2) ^ asw));
        bf16x8 b0 = *reinterpret_cast<const bf16x8*>(Bp + k0);
        bf16x8 b1 = *reinterpret_cast<const bf16x8*>(Bp + 16*KTOT + k0);
        bf16x8 b2 = *reinterpret_cast<const bf16x8*>(Bp + 32*KTOT + k0);
        bf16x8 b3 = *reinterpret_cast<const bf16x8*>(Bp + 48*KTOT + k0);
        acc0 = __builtin_amdgcn_mfma_f32_16x16x32_bf16(a, b0, acc0, 0, 0, 0);
        acc1 = __builtin_amdgcn_mfma_f32_16x16x32_bf16(a, b1, acc1, 0, 0, 0);
        acc2 = __builtin_amdgcn_mfma_f32_16x16x32_bf16(a, b2, acc2, 0, 0, 0);
        acc3 = __builtin_amdgcn_mfma_f32_16x16x32_bf16(a, b3, acc3, 0, 0, 0);
    }
    // residual: k' = 2048..2303 from qe (f32 -> bf16 on the fly)
    const float* Qp = qe + (size_t)(m0 + lrow)*256 + lk*8;
    #pragma unroll
    for (int k0 = 0; k0 < 256; k0 += 32){
        float4 qa = *reinterpret_cast<const float4*>(Qp + k0);
        float4 qb = *reinterpret_cast<const float4*>(Qp + k0 + 4);
        union { unsigned short u[8]; bf16x8 v; } cu;
        cu.u[0]=f2bf(qa.x); cu.u[1]=f2bf(qa.y); cu.u[2]=f2bf(qa.z); cu.u[3]=f2bf(qa.w);
        cu.u[4]=f2bf(qb.x); cu.u[5]=f2bf(qb.y); cu.u[6]=f2bf(qb.z); cu.u[7]=f2bf(qb.w);
        bf16x8 b0 = *reinterpret_cast<const bf16x8*>(Bp + 2048 + k0);
        bf16x8 b1 = *reinterpret_cast<const bf16x8*>(Bp + 16*KTOT + 2048 + k0);
        bf16x8 b2 = *reinterpret_cast<const bf16x8*>(Bp + 32*KTOT + 2048 + k0);
        bf16x8 b3 = *reinterpret_cast<const bf16x8*>(Bp + 48*KTOT + 2048 + k0);
        acc0 = __builtin_amdgcn_mfma_f32_16x16x32_bf16(cu.v, b0, acc0, 0, 0, 0);
        acc1 = __builtin_amdgcn_mfma_f32_16x16x32_bf16(cu.v, b1, acc1, 0, 0, 0);
        acc2 = __builtin_amdgcn_mfma_f32_16x16x32_bf16(cu.v, b2, acc2, 0, 0, 0);
        acc3 = __builtin_amdgcn_mfma_f32_16x16x32_bf16(cu.v, b3, acc3, 0, 0, 0);
    }

    // epilogue: + bconst + wsb@Bh
    float wsrow[4][8];
    #pragma unroll
    for (int i = 0; i < 4; i++){
        int r = m0 + lk*4 + i;
        float4 wa = *reinterpret_cast<const float4*>(wsb + (size_t)r*8);
        float4 wb = *reinterpret_cast<const float4*>(wsb + (size_t)r*8 + 4);
        wsrow[i][0]=wa.x; wsrow[i][1]=wa.y; wsrow[i][2]=wa.z; wsrow[i][3]=wa.w;
        wsrow[i][4]=wb.x; wsrow[i][5]=wb.y; wsrow[i][6]=wb.z; wsrow[i][7]=wb.w;
    }
    const f32x4 accs[4] = {acc0, acc1, acc2, acc3};
    #pragma unroll
    for (int nt = 0; nt < 4; nt++){
        int c = w*64 + nt*16 + lrow;
        float bcv = bconst[c];
        float bhv[8];
        #pragma unroll
        for (int h = 0; h < 8; h++) bhv[h] = Bh[h*256 + c];
        #pragma unroll
        for (int i = 0; i < 4; i++){
            int r = m0 + lk*4 + i;
            float v = accs[nt][i] + bcv;
            #pragma unroll
            for (int h = 0; h < 8; h++) v += wsrow[i][h]*bhv[h];
            out[(size_t)r*256 + c] = v;
        }
    }
}

extern "C" void kernel_launch(void* const* d_in, const int* in_sizes, int n_in,
                              void* d_out, int out_size, void* d_ws, size_t ws_size,
                              hipStream_t stream)
{
    (void)in_sizes; (void)n_in; (void)out_size;
    float* out = (float*)d_out;
    char*  ws  = (char*)d_ws;

    // workspace layout (256B-aligned); bevT last so the fallback tier works
    const size_t OF_CO  = 0;                                  // coords 4096*8*48
    const size_t OF_WSB = OF_CO  + (size_t)4096*8*48;         //  1,572,864
    const size_t OF_WGT = OF_WSB + (size_t)4096*8*4;          //  1,703,936
    const size_t OF_BH  = OF_WGT + (size_t)256*KTOT*2;        //  2,883,584
    const size_t OF_BC  = OF_BH  + (size_t)8*256*4;           //  2,891,776
    const size_t OF_G   = OF_BC  + 1024;                      //  2,892,800
    const size_t OF_BT  = OF_G   + (size_t)4096*2048*2;       // 19,670,016
    const size_t NEED   = OF_BT  + (size_t)BB*HWF*DD*2;       // 101,590,016

    float*          coords = (float*)(ws + OF_CO);
    float*          wsb    = (float*)(ws + OF_WSB);
    unsigned short* WgT    = (unsigned short*)(ws + OF_WGT);
    float*          Bh     = (float*)(ws + OF_BH);
    float*          bconst = (float*)(ws + OF_BC);
    unsigned short* g      = (unsigned short*)(ws + OF_G);
    unsigned short* bevT   = (unsigned short*)(ws + OF_BT);

    const float* qe    = (const float*)d_in[0];
    const float* ctrl  = (const float*)d_in[1];
    const float* bev   = (const float*)d_in[2];
    const float* pc    = (const float*)d_in[4];
    const float* Wq    = (const float*)d_in[5];
    const float* bq    = (const float*)d_in[6];
    const float* Wval  = (const float*)d_in[7];
    const float* bval  = (const float*)d_in[8];
    const float* Woff  = (const float*)d_in[9];
    const float* boff  = (const float*)d_in[10];
    const float* Wattn = (const float*)d_in[11];
    const float* battn = (const float*)d_in[12];
    const float* Wdo   = (const float*)d_in[13];
    const float* bdo   = (const float*)d_in[14];
    const float* Wout  = (const float*)d_in[15];
    const float* bout  = (const float*)d_in[16];

    const bool haveT = (ws_size >= NEED);

    // K1: oa (64) + prep (49) + transpose (10000) in one grid
    front_kernel<<<haveT ? 10113 : 113, 256, 0, stream>>>(
        qe, ctrl, pc, Wq, bq, Wval, bval, Woff, boff, Wattn, battn,
        Wdo, bdo, Wout, bout, bev, bevT, WgT, Bh, bconst, coords, wsb);
    // K2: gather
    if (haveT)
        gather_kernel<true ><<<2048, 256, 0, stream>>>(bevT, bev, coords, g);
    else
        gather_kernel<false><<<2048, 256, 0, stream>>>(bevT, bev, coords, g);
    // K3: fused back-end GEMM (MFMA bf16)
    final_kernel<<<256, 256, 0, stream>>>(g, qe, WgT, wsb, Bh, bconst, out);
}